// Round 26
// baseline (420.892 us; speedup 1.0000x reference)
//
#include <hip/hip_runtime.h>
#include <hip/hip_bf16.h>

// B=8, H=W=64, C=128, rate=2 -> k=3, h=w=32, L=1024
// Workspace (72,433,664 bytes), time-multiplexed (liveness checked):
//  phase A: Tbuf(corr out) [0,33.55M); sp [33.55,38.29M) invd [38.29,38.81M)
//           sp16 [38.81,41.18M) bf16 [41.18,60.06M)
//  fsm:     reads Tbuf -> out_c + yp16 [33.55,50.33M)
//  deconv:  bp16 [0,18.87M) (after fsm), yup [50.33,67.11M)
//  phase C/D: SM [0,16.78M) P316 [16.78,25.70M) P316B [25.70,34.62M)
//             X16 [42.48,51.40M)  (overlaps stream-ordered)
//  static:  wt1 [69.24M) wt2 [69.83M) pw1 [71.01M) pw2 [71.04M) m0/mm [71.11M)

#define BOFF_T       0
#define BOFF_SP      33554432
#define BOFF_INVD    38289408
#define BOFF_SP16    38813696
#define BOFF_BF16    41181184
#define BOFF_YP16    33554432
#define BOFF_BP16    0
#define BOFF_YUP     50331648
#define BOFF_SM      0
#define BOFF_P316    16777216
#define BOFF_P316B   25698304
#define BOFF_X16     42475520
#define BOFF_WT1     69238784
#define BOFF_WT2     69828608
#define BOFF_PW1     71008256
#define BOFF_PW2     71041024
#define BOFF_M0      71106560
#define BOFF_MM      71139328

typedef float f32x4 __attribute__((ext_vector_type(4)));
typedef _Float16 f16x8 __attribute__((ext_vector_type(8)));

__global__ __launch_bounds__(256) void k_mask_pool(const float* __restrict__ mask, float* __restrict__ m0) {
    int blk = blockIdx.x;
    int b = blk >> 10, pq = blk & 1023, p = pq >> 5, q = pq & 31;
    int t = threadIdx.x, dy = t >> 4, dx = t & 15;
    float v = mask[((size_t)(b * 512 + p * 16 + dy)) * 512 + q * 16 + dx];
#pragma unroll
    for (int o = 32; o; o >>= 1) v = fmaxf(v, __shfl_xor(v, o));
    __shared__ float s[4];
    if ((t & 63) == 0) s[t >> 6] = v;
    __syncthreads();
    if (t == 0) m0[blk] = fmaxf(fmaxf(s[0], s[1]), fmaxf(s[2], s[3]));
}

__global__ void k_mask_dilate(const float* __restrict__ m0, float* __restrict__ mm) {
    int idx = blockIdx.x * 256 + threadIdx.x;
    if (idx >= 8192) return;
    int b = idx >> 10, pq = idx & 1023, p = pq >> 5, q = pq & 31;
    float v = -1e30f;
    for (int di = -1; di <= 1; ++di)
        for (int dj = -1; dj <= 1; ++dj) {
            int pp = p + di, qq = q + dj;
            if (pp >= 0 && pp < 32 && qq >= 0 && qq < 32)
                v = fmaxf(v, m0[(b << 10) + pp * 32 + qq]);
        }
    mm[idx] = 1.0f - v;
}

// srcpad + fp16 conversion fused (single pass)
__global__ void k_srcpad(const float* __restrict__ x, float* __restrict__ sp,
                         _Float16* __restrict__ sp16) {
    int idx = blockIdx.x * 256 + threadIdx.x;
    if (idx >= 8 * 34 * 34 * 128) return;
    int c = idx & 127;
    int r = idx >> 7;
    int xx = r % 34; r /= 34;
    int yy = r % 34; int b = r / 34;
    float v = 0.f;
    if (yy >= 1 && yy <= 32 && xx >= 1 && xx <= 32)
        v = x[(((size_t)(b * 64 + (yy - 1) * 2)) * 64 + (xx - 1) * 2) * 128 + c];
    sp[idx] = v;
    sp16[idx] = (_Float16)v;
}

__global__ void k_invd(const float* __restrict__ sp, float* __restrict__ invd) {
    int idx = blockIdx.x * 256 + threadIdx.x;
    if (idx >= 1024 * 128) return;
    int c = idx & 127, l = idx >> 7, lh = l >> 5, lw = l & 31;
    float s = 0.f;
    for (int b = 0; b < 8; ++b)
#pragma unroll
        for (int i = 0; i < 3; ++i)
#pragma unroll
            for (int j = 0; j < 3; ++j) {
                float v = sp[(((size_t)(b * 34 + lh + i)) * 34 + (lw + j)) * 128 + c];
                s += v * v;
            }
    invd[idx] = 1.0f / fmaxf(s, 1e-8f);
}

// Bf16[b][l][ij][c] = sp[b][lh+i][lw+j][c] * invd[l][c], fp16.
__global__ void k_corr_B16(const float* __restrict__ sp, const float* __restrict__ invd,
                           _Float16* __restrict__ bf) {
    int idx = blockIdx.x * 256 + threadIdx.x;
    if (idx >= 1179648) return;
    int c8 = idx & 15; int rest = idx >> 4;
    int ij = rest % 9; int rest2 = rest / 9;
    int l = rest2 & 1023, b = rest2 >> 10;
    int lh = l >> 5, lw = l & 31;
    int i = (ij >= 6) ? 2 : (ij >= 3 ? 1 : 0);
    int j = ij - 3 * i;
    int c0 = c8 * 8;
    const float* s = sp + (((size_t)(b * 34 + lh + i)) * 34 + (lw + j)) * 128 + c0;
    const float* dv = invd + l * 128 + c0;
    f16x8 h;
#pragma unroll
    for (int u = 0; u < 8; ++u) h[u] = (_Float16)(s[u] * dv[u]);
    size_t off = ((size_t)(b * 1024 + l)) * 1152 + ij * 128 + c0;
    *reinterpret_cast<f16x8*>(bf + off) = h;
}

// Bp16[b][ij][c][l] = x[b][2lh+ip][2lw+jp][c] (0 OOB), fp16.
__global__ void k_deconv_B16(const float* __restrict__ x, _Float16* __restrict__ bp) {
    int idx = blockIdx.x * 256 + threadIdx.x;
    if (idx >= 1179648) return;
    int l8 = idx & 127; int rest = idx >> 7;
    int c = rest & 127; int rest2 = rest >> 7;
    int ij = rest2 % 9; int b = rest2 / 9;
    int ip = (ij >= 6) ? 2 : (ij >= 3 ? 1 : 0);
    int jp = ij - 3 * ip;
    int l0 = l8 * 8;
    int lh = l0 >> 5, lw0 = l0 & 31;
    int rr = 2 * lh + ip;
    f16x8 h;
#pragma unroll
    for (int u = 0; u < 8; ++u) {
        int ss = 2 * (lw0 + u) + jp;
        float v = (rr < 64 && ss < 64) ? x[(((size_t)(b * 64 + rr)) * 64 + ss) * 128 + c] : 0.f;
        h[u] = (_Float16)v;
    }
    size_t off = (((size_t)(b * 9 + ij)) * 128 + c) * 1024 + l0;
    *reinterpret_cast<f16x8*>(bp + off) = h;
}

// corr MFMA fp16: M-tile 32, N-tile 128, K-step 64, 256 thr / 4 waves
// (each wave 2 mf x 2 nn), depth-2 prefetch, XCD-swizzled grid (2048) -> 8 blk/CU.
// Threads split: tid<128 stage K-half A (Aa), tid>=128 stage K-half B (Ab).
__global__ __launch_bounds__(256) void k_corr_mfma(const _Float16* __restrict__ sp16,
                                                   const _Float16* __restrict__ bf,
                                                   float* __restrict__ outy) {
    const int bid = blockIdx.x;
    const int xcd = bid & 7, slot = bid >> 3;   // slot in [0,256)
    const int tm = slot & 31, pg = slot >> 5;   // pg in [0,8)
    const int panel = pg * 8 + xcd;             // [0,64)
    const int b = panel >> 3, tn = panel & 7;
    __shared__ _Float16 Aa[32][40];
    __shared__ _Float16 Ab[32][40];
    const int tid = threadIdx.x;
    const int w = tid >> 6, lane = tid & 63, m = lane & 15, g = lane >> 4;
    f32x4 acc[2][2];
#pragma unroll
    for (int mf = 0; mf < 2; ++mf)
#pragma unroll
        for (int nn = 0; nn < 2; ++nn) acc[mf][nn] = f32x4{0.f, 0.f, 0.f, 0.f};
    const int shalf = tid >> 7;                 // which K-half this thread stages
    const int tl = tid & 127;
    const int srow = tl >> 2, scc = (tl & 3) * 8;
    const int pq = tm * 32 + srow, p = pq >> 5, q = pq & 31;
    const int col0 = tn * 128 + w * 32 + m;
    const size_t boff0 = ((size_t)b * 1024 + col0) * 1152 + g * 8;
    const size_t boff1 = ((size_t)b * 1024 + col0 + 16) * 1152 + g * 8;
    _Float16* sdst = shalf ? &Ab[srow][scc] : &Aa[srow][scc];

    auto aoff = [&](int ktAbs) -> size_t {
        int ij = ktAbs >> 7;
        int i = (ij >= 6) ? 2 : (ij >= 3 ? 1 : 0);
        int j = ij - 3 * i;
        int c0 = (ktAbs & 127) + scc;
        return (((size_t)(b * 34 + p + i)) * 34 + (q + j)) * 128 + c0;
    };
    const int hk = shalf * 32;
    f16x8 aq  = *reinterpret_cast<const f16x8*>(sp16 + aoff(hk));
    f16x8 aq2 = *reinterpret_cast<const f16x8*>(sp16 + aoff(64 + hk));
    f16x8 b0q_a = *reinterpret_cast<const f16x8*>(bf + boff0);
    f16x8 b0q_b = *reinterpret_cast<const f16x8*>(bf + boff0 + 32);
    f16x8 b1q_a = *reinterpret_cast<const f16x8*>(bf + boff1);
    f16x8 b1q_b = *reinterpret_cast<const f16x8*>(bf + boff1 + 32);
    f16x8 b0q2_a = *reinterpret_cast<const f16x8*>(bf + boff0 + 64);
    f16x8 b0q2_b = *reinterpret_cast<const f16x8*>(bf + boff0 + 96);
    f16x8 b1q2_a = *reinterpret_cast<const f16x8*>(bf + boff1 + 64);
    f16x8 b1q2_b = *reinterpret_cast<const f16x8*>(bf + boff1 + 96);

    for (int kt = 0; kt < 1152; kt += 64) {
        __syncthreads();
        *reinterpret_cast<f16x8*>(sdst) = aq;
        __syncthreads();
        const int kt2 = (kt + 128 < 1152) ? kt + 128 : kt;
        f16x8 cb0a = b0q_a, cb0b = b0q_b, cb1a = b1q_a, cb1b = b1q_b;
        aq = aq2;
        aq2 = *reinterpret_cast<const f16x8*>(sp16 + aoff(kt2 + hk));
        b0q_a = b0q2_a; b0q_b = b0q2_b;
        b1q_a = b1q2_a; b1q_b = b1q2_b;
        b0q2_a = *reinterpret_cast<const f16x8*>(bf + boff0 + kt2);
        b0q2_b = *reinterpret_cast<const f16x8*>(bf + boff0 + kt2 + 32);
        b1q2_a = *reinterpret_cast<const f16x8*>(bf + boff1 + kt2);
        b1q2_b = *reinterpret_cast<const f16x8*>(bf + boff1 + kt2 + 32);

        f16x8 av;
#pragma unroll
        for (int mf = 0; mf < 2; ++mf) {
            av = *reinterpret_cast<const f16x8*>(&Aa[mf * 16 + m][g * 8]);
            acc[mf][0] = __builtin_amdgcn_mfma_f32_16x16x32_f16(av, cb0a, acc[mf][0], 0, 0, 0);
            acc[mf][1] = __builtin_amdgcn_mfma_f32_16x16x32_f16(av, cb1a, acc[mf][1], 0, 0, 0);
            av = *reinterpret_cast<const f16x8*>(&Ab[mf * 16 + m][g * 8]);
            acc[mf][0] = __builtin_amdgcn_mfma_f32_16x16x32_f16(av, cb0b, acc[mf][0], 0, 0, 0);
            acc[mf][1] = __builtin_amdgcn_mfma_f32_16x16x32_f16(av, cb1b, acc[mf][1], 0, 0, 0);
        }
    }
#pragma unroll
    for (int mf = 0; mf < 2; ++mf) {
        int row = tm * 32 + mf * 16 + g * 4;
#pragma unroll
        for (int nn = 0; nn < 2; ++nn) {
            int col = col0 + nn * 16;
#pragma unroll
            for (int r = 0; r < 4; ++r)
                outy[((size_t)b << 20) + (size_t)(row + r) * 1024 + col] = acc[mf][nn][r];
        }
    }
}

// deconv MFMA fp16: M-tile 32, K-step 64, 256 thr / 4 waves (2 mf x 2 nn),
// depth-2 prefetch, XCD=batch mapping. Grid 2304 -> 9 blocks/CU.
__global__ __launch_bounds__(256) void k_deconv_mfma(const _Float16* __restrict__ yp16,
                                                     const _Float16* __restrict__ bp,
                                                     float* __restrict__ yup) {
    const int bid = blockIdx.x;
    const int b = bid & 7;                      // xcd == batch
    const int slot = bid >> 3;                  // [0,288)
    const int tn = slot % 9;
    const int tm = slot / 9;                    // [0,32)
    __shared__ _Float16 Aa[32][40];
    __shared__ _Float16 Ab[32][40];
    const int tid = threadIdx.x;
    const int w = tid >> 6, lane = tid & 63, m = lane & 15, g = lane >> 4;
    f32x4 acc[2][2];
#pragma unroll
    for (int mf = 0; mf < 2; ++mf)
#pragma unroll
        for (int nn = 0; nn < 2; ++nn) acc[mf][nn] = f32x4{0.f, 0.f, 0.f, 0.f};
    const int shalf = tid >> 7;
    const int tl = tid & 127;
    const int srow = tl >> 2, scc = (tl & 3) * 8;
    const int c0 = w * 32 + m;
    const int hk = shalf * 32;
    const _Float16* abase = yp16 + ((size_t)b << 20) + (size_t)(tm * 32 + srow) * 1024 + scc + hk;
    const size_t boff0 = (((size_t)(b * 9 + tn)) * 128 + c0) * 1024 + g * 8;
    const size_t boff1 = (((size_t)(b * 9 + tn)) * 128 + c0 + 16) * 1024 + g * 8;
    _Float16* sdst = shalf ? &Ab[srow][scc] : &Aa[srow][scc];

    f16x8 aq  = *reinterpret_cast<const f16x8*>(abase);
    f16x8 aq2 = *reinterpret_cast<const f16x8*>(abase + 64);
    f16x8 b0q_a = *reinterpret_cast<const f16x8*>(bp + boff0);
    f16x8 b0q_b = *reinterpret_cast<const f16x8*>(bp + boff0 + 32);
    f16x8 b1q_a = *reinterpret_cast<const f16x8*>(bp + boff1);
    f16x8 b1q_b = *reinterpret_cast<const f16x8*>(bp + boff1 + 32);
    f16x8 b0q2_a = *reinterpret_cast<const f16x8*>(bp + boff0 + 64);
    f16x8 b0q2_b = *reinterpret_cast<const f16x8*>(bp + boff0 + 96);
    f16x8 b1q2_a = *reinterpret_cast<const f16x8*>(bp + boff1 + 64);
    f16x8 b1q2_b = *reinterpret_cast<const f16x8*>(bp + boff1 + 96);

    for (int kt = 0; kt < 1024; kt += 64) {
        __syncthreads();
        *reinterpret_cast<f16x8*>(sdst) = aq;
        __syncthreads();
        const int kt2 = (kt + 128 < 1024) ? kt + 128 : kt;
        f16x8 cb0a = b0q_a, cb0b = b0q_b, cb1a = b1q_a, cb1b = b1q_b;
        aq = aq2;
        aq2 = *reinterpret_cast<const f16x8*>(abase + kt2);
        b0q_a = b0q2_a; b0q_b = b0q2_b;
        b1q_a = b1q2_a; b1q_b = b1q2_b;
        b0q2_a = *reinterpret_cast<const f16x8*>(bp + boff0 + kt2);
        b0q2_b = *reinterpret_cast<const f16x8*>(bp + boff0 + kt2 + 32);
        b1q2_a = *reinterpret_cast<const f16x8*>(bp + boff1 + kt2);
        b1q2_b = *reinterpret_cast<const f16x8*>(bp + boff1 + kt2 + 32);

        f16x8 av;
#pragma unroll
        for (int mf = 0; mf < 2; ++mf) {
            av = *reinterpret_cast<const f16x8*>(&Aa[mf * 16 + m][g * 8]);
            acc[mf][0] = __builtin_amdgcn_mfma_f32_16x16x32_f16(av, cb0a, acc[mf][0], 0, 0, 0);
            acc[mf][1] = __builtin_amdgcn_mfma_f32_16x16x32_f16(av, cb1a, acc[mf][1], 0, 0, 0);
            av = *reinterpret_cast<const f16x8*>(&Ab[mf * 16 + m][g * 8]);
            acc[mf][0] = __builtin_amdgcn_mfma_f32_16x16x32_f16(av, cb0b, acc[mf][0], 0, 0, 0);
            acc[mf][1] = __builtin_amdgcn_mfma_f32_16x16x32_f16(av, cb1b, acc[mf][1], 0, 0, 0);
        }
    }
    const int ip = (tn >= 6) ? 2 : (tn >= 3 ? 1 : 0);
    const int jp = tn - 3 * ip;
#pragma unroll
    for (int mf = 0; mf < 2; ++mf) {
        int uvb = tm * 32 + mf * 16 + g * 4;
#pragma unroll
        for (int nn = 0; nn < 2; ++nn) {
            int c = c0 + nn * 16;
#pragma unroll
            for (int r = 0; r < 4; ++r) {
                int uv = uvb + r;
                int uu = uv >> 5, vv = uv & 31;
                int P = 2 * uu + ip, Q = 2 * vv + jp;
                if (P < 64 && Q < 64)
                    atomicAdd(&yup[(((size_t)(b * 64 + P)) * 64 + Q) * 128 + c], acc[mf][nn][r]);
            }
        }
    }
}

// FUSED fuse1+fuse2+softmax.
__global__ __launch_bounds__(256) void k_fsm(const float* __restrict__ y,
                                             const float* __restrict__ mm,
                                             float* __restrict__ outc,
                                             _Float16* __restrict__ yp16) {
    int row = blockIdx.x;               // b*1024 + s
    int b = row >> 10, s = row & 1023;
    const float* base = y + ((size_t)b << 20);
    float mmv = mm[row];
    int t0 = threadIdx.x;
    const int m0 = ((s & 31) << 5) + (s >> 5);
    float vals[4];
    float mx = -1e30f;
#pragma unroll
    for (int i = 0; i < 4; ++i) {
        int t = t0 + i * 256;
        int n0 = ((t & 31) << 5) + (t >> 5);
        float v = 0.f;
#pragma unroll
        for (int d = -1; d <= 1; ++d) {
            int mm_ = m0 + d, nn_ = n0 + d;
            if (mm_ >= 0 && mm_ < 1024 && nn_ >= 0 && nn_ < 1024) {
                int a = ((mm_ & 31) << 5) + (mm_ >> 5);
                int c = ((nn_ & 31) << 5) + (nn_ >> 5);
                float zv = base[(size_t)a * 1024 + c];
                if (a > 0 && c > 0) zv += base[(size_t)(a - 1) * 1024 + (c - 1)];
                if (a < 1023 && c < 1023) zv += base[(size_t)(a + 1) * 1024 + (c + 1)];
                v += zv;
            }
        }
        vals[i] = v * mmv * 10.0f;
        mx = fmaxf(mx, vals[i]);
    }
#pragma unroll
    for (int o = 32; o; o >>= 1) mx = fmaxf(mx, __shfl_xor(mx, o));
    __shared__ float red[8];
    if ((t0 & 63) == 0) red[t0 >> 6] = mx;
    __syncthreads();
    mx = fmaxf(fmaxf(red[0], red[1]), fmaxf(red[2], red[3]));
    float ssum = 0.f;
#pragma unroll
    for (int i = 0; i < 4; ++i) {
        vals[i] = expf(vals[i] - mx);
        ssum += vals[i];
    }
#pragma unroll
    for (int o = 32; o; o >>= 1) ssum += __shfl_xor(ssum, o);
    if ((t0 & 63) == 0) red[4 + (t0 >> 6)] = ssum;
    __syncthreads();
    ssum = red[4] + red[5] + red[6] + red[7];
    float inv = mmv / ssum;
#pragma unroll
    for (int i = 0; i < 4; ++i) {
        float pv = vals[i] * inv;
        outc[(size_t)row * 1024 + t0 + i * 256] = pv;
        yp16[(size_t)row * 1024 + t0 + i * 256] = (_Float16)pv;
    }
}

// f32 image (8,64,64,128) -> padded fp16 (8,66,66,128), zero halo
__global__ __launch_bounds__(256) void k_pad16(const float* __restrict__ in,
                                               _Float16* __restrict__ o) {
    int idx = blockIdx.x * 256 + threadIdx.x;
    int c8 = idx & 15;
    int r = idx >> 4;
    int pc = r % 66; r /= 66;
    int pr = r % 66; int b = r / 66;
    f16x8 h;
    if (pr >= 1 && pr <= 64 && pc >= 1 && pc <= 64) {
        const float* s = in + (((size_t)(b * 64 + pr - 1)) * 64 + (pc - 1)) * 128 + c8 * 8;
        float4 v0 = *reinterpret_cast<const float4*>(s);
        float4 v1 = *reinterpret_cast<const float4*>(s + 4);
        h[0] = (_Float16)v0.x; h[1] = (_Float16)v0.y; h[2] = (_Float16)v0.z; h[3] = (_Float16)v0.w;
        h[4] = (_Float16)v1.x; h[5] = (_Float16)v1.y; h[6] = (_Float16)v1.z; h[7] = (_Float16)v1.w;
    } else {
#pragma unroll
        for (int u = 0; u < 8; ++u) h[u] = (_Float16)0.f;
    }
    *reinterpret_cast<f16x8*>(o + (size_t)idx * 8) = h;
}

// (3,3,CI,128) f32 -> [9][co=128][ci] fp16
__global__ void k_wt16(const float* __restrict__ w, _Float16* __restrict__ o, int CI) {
    int idx = blockIdx.x * 256 + threadIdx.x;
    if (idx >= 9 * CI * 128) return;
    int ci = idx % CI; int rest = idx / CI;
    int co = rest & 127; int ij = rest >> 7;
    o[idx] = (_Float16)w[((size_t)ij * CI + ci) * 128 + co];
}

// pw (1,1,CI,128) f32 -> transposed fp16 [co][ci]
__global__ void k_pw16(const float* __restrict__ pw, _Float16* __restrict__ out, int CI) {
    int idx = blockIdx.x * 256 + threadIdx.x;
    if (idx >= CI * 128) return;
    int co = idx & 127, ci = idx >> 7;
    out[(size_t)co * CI + ci] = (_Float16)pw[idx];
}

// Fused depthwise 3x3 + pointwise (fp16 MFMA) + channel softmax -> smout f32.
// HALF-ROW blocks (32 px): grid 1024 = (b,P,half), 4 blocks/CU, dwacc CI/8 regs.
template <int CI>
__global__ __launch_bounds__(256) void k_dwpw_mfma(const _Float16* __restrict__ in0,
                                                   const _Float16* __restrict__ in1,
                                                   const float* __restrict__ dwW,
                                                   const _Float16* __restrict__ pwt,
                                                   const float* __restrict__ db,
                                                   float* __restrict__ smout) {
    const int bid = blockIdx.x;
    const int swz = (bid & 7) * 128 + (bid >> 3);   // XCD-contiguous
    const int b = swz >> 7;
    const int rem = swz & 127;
    const int P = rem >> 1, half = rem & 1;
    const int Q0 = half * 32;
    const int t = threadIdx.x;
    const int w = t >> 6, lane = t & 63, m = lane & 15, g = lane >> 4;
    __shared__ _Float16 Adw[32 * CI];
    __shared__ float red[2][4][32];
    char* ab = (char*)Adw;
    const int px = t & 31;
    const int grp = t >> 5;
    const int cb = grp * (CI / 8);
    float dwacc[CI / 8];
#pragma unroll
    for (int u = 0; u < CI / 8; ++u) dwacc[u] = 0.f;
#pragma unroll
    for (int i = 0; i < 3; ++i) {
#pragma unroll
        for (int j = 0; j < 3; ++j) {
            const int ij = i * 3 + j;
#pragma unroll
            for (int c8 = 0; c8 < CI / 64; ++c8) {
                const int c = cb + c8 * 8;
                const _Float16* ph = (CI == 256 && c >= 128) ? in1 : in0;
                const int cc = (CI == 256 && c >= 128) ? (c - 128) : c;
                size_t off = (((size_t)b * 66 + P + i) * 66 + Q0 + px + j) * 128 + cc;
                f16x8 vh = *reinterpret_cast<const f16x8*>(ph + off);
#pragma unroll
                for (int u = 0; u < 8; ++u)
                    dwacc[c8 * 8 + u] = fmaf((float)vh[u], dwW[ij * CI + c + u], dwacc[c8 * 8 + u]);
            }
        }
    }
#pragma unroll
    for (int c8 = 0; c8 < CI / 64; ++c8) {
        f16x8 hv;
#pragma unroll
        for (int u = 0; u < 8; ++u) hv[u] = (_Float16)dwacc[c8 * 8 + u];
        int byte = px * (CI * 2) + (cb + c8 * 8) * 2;
        int sz = byte ^ ((px & 7) << 4);
        *reinterpret_cast<f16x8*>(ab + sz) = hv;
    }
    __syncthreads();
    f32x4 acc[2][2];
#pragma unroll
    for (int mt = 0; mt < 2; ++mt)
#pragma unroll
        for (int nn = 0; nn < 2; ++nn) acc[mt][nn] = f32x4{0.f, 0.f, 0.f, 0.f};
    const int co0 = w * 32 + m;
#pragma unroll
    for (int kc = 0; kc < CI / 32; ++kc) {
        f16x8 av[2];
#pragma unroll
        for (int mt = 0; mt < 2; ++mt) {
            int prow = mt * 16 + m;
            int byte = prow * (CI * 2) + (kc * 32 + g * 8) * 2;
            int sz = byte ^ ((prow & 7) << 4);
            av[mt] = *reinterpret_cast<const f16x8*>(ab + sz);
        }
#pragma unroll
        for (int nn = 0; nn < 2; ++nn) {
            f16x8 bv = *reinterpret_cast<const f16x8*>(pwt + (size_t)(co0 + nn * 16) * CI + kc * 32 + g * 8);
#pragma unroll
            for (int mt = 0; mt < 2; ++mt)
                acc[mt][nn] = __builtin_amdgcn_mfma_f32_16x16x32_f16(av[mt], bv, acc[mt][nn], 0, 0, 0);
        }
    }
    float db0 = db[co0], db1 = db[co0 + 16];
    float mx[2][4];
#pragma unroll
    for (int mt = 0; mt < 2; ++mt)
#pragma unroll
        for (int r = 0; r < 4; ++r) {
            acc[mt][0][r] += db0;
            acc[mt][1][r] += db1;
            float v = fmaxf(acc[mt][0][r], acc[mt][1][r]);
#pragma unroll
            for (int o = 1; o <= 8; o <<= 1) v = fmaxf(v, __shfl_xor(v, o));
            mx[mt][r] = v;
        }
    if (m == 0) {
#pragma unroll
        for (int mt = 0; mt < 2; ++mt)
#pragma unroll
            for (int r = 0; r < 4; ++r) red[0][w][mt * 16 + g * 4 + r] = mx[mt][r];
    }
    __syncthreads();
    float sume[2][4];
#pragma unroll
    for (int mt = 0; mt < 2; ++mt)
#pragma unroll
        for (int r = 0; r < 4; ++r) {
            int p = mt * 16 + g * 4 + r;
            float M = fmaxf(fmaxf(red[0][0][p], red[0][1][p]), fmaxf(red[0][2][p], red[0][3][p]));
            acc[mt][0][r] = expf(acc[mt][0][r] - M);
            acc[mt][1][r] = expf(acc[mt][1][r] - M);
            float s = acc[mt][0][r] + acc[mt][1][r];
#pragma unroll
            for (int o = 1; o <= 8; o <<= 1) s += __shfl_xor(s, o);
            sume[mt][r] = s;
        }
    if (m == 0) {
#pragma unroll
        for (int mt = 0; mt < 2; ++mt)
#pragma unroll
            for (int r = 0; r < 4; ++r) red[1][w][mt * 16 + g * 4 + r] = sume[mt][r];
    }
    __syncthreads();
#pragma unroll
    for (int mt = 0; mt < 2; ++mt)
#pragma unroll
        for (int r = 0; r < 4; ++r) {
            int p = mt * 16 + g * 4 + r;
            float S = red[1][0][p] + red[1][1][p] + red[1][2][p] + red[1][3][p];
            float inv = 1.0f / S;
            size_t pix = ((size_t)b * 64 + P) * 64 + Q0 + p;
            smout[pix * 128 + co0] = acc[mt][0][r] * inv;
            smout[pix * 128 + co0 + 16] = acc[mt][1][r] * inv;
        }
}

// fp16 implicit-GEMM 3x3 conv + bias + elu + gate, LDS-staged rows.
// W16=1: write fp16 directly into padded (8,66,66,128) buffer (interior).
template <int CI, int W16>
__global__ __launch_bounds__(256, 4) void k_conv_lds(const _Float16* __restrict__ in0,
                                                     const _Float16* __restrict__ in1,
                                                     const _Float16* __restrict__ wt,
                                                     const float* __restrict__ bias,
                                                     const float* __restrict__ sm,
                                                     float* __restrict__ out,
                                                     _Float16* __restrict__ out16) {
    const int bid = blockIdx.x;
    const int idx = (bid & 7) * 128 + (bid >> 3);
    const int row = idx >> 1, cohalf = idx & 1;
    const int b = row >> 6, P = row & 63;
    const int tid = threadIdx.x;
    const int w = tid >> 6, lane = tid & 63;
    const int m = lane & 15, g = lane >> 4;
    __shared__ _Float16 S[66 * 128];
    char* sb = (char*)S;
    f32x4 acc[4];
#pragma unroll
    for (int mt = 0; mt < 4; ++mt) acc[mt] = f32x4{0.f, 0.f, 0.f, 0.f};
    const int cow = cohalf * 64 + w * 16 + m;

#pragma unroll
    for (int half = 0; half < CI / 128; ++half) {
        const _Float16* ih = (half == 0) ? in0 : in1;
        const size_t rbase0 = ((size_t)b * 66 + P) * 66 * 128;
#pragma unroll
        for (int i = 0; i < 3; ++i) {
            __syncthreads();
            const size_t rsrc = rbase0 + (size_t)i * 66 * 128;
#pragma unroll
            for (int e0 = 0; e0 < 1056; e0 += 256) {
                int e = e0 + tid;
                if (e < 1056) {
                    int px = e >> 4, c8 = e & 15;
                    int lin = px * 256 + c8 * 16;
                    int sz = lin ^ ((px & 7) << 4);
                    size_t so = rsrc + (size_t)px * 128 + c8 * 8;
                    *reinterpret_cast<f16x8*>(sb + sz) = *reinterpret_cast<const f16x8*>(ih + so);
                }
            }
            __syncthreads();
#pragma unroll
            for (int j = 0; j < 3; ++j) {
                const int ij = i * 3 + j;
                const _Float16* wp = wt + ((size_t)ij * 128 + cow) * CI + half * 128 + g * 8;
#pragma unroll
                for (int ci0 = 0; ci0 < 128; ci0 += 32) {
                    f16x8 bv = *reinterpret_cast<const f16x8*>(wp + ci0);
                    f16x8 av[4];
#pragma unroll
                    for (int mt = 0; mt < 4; ++mt) {
                        int px = mt * 16 + m + j;
                        int lin = px * 256 + ci0 * 2 + g * 16;
                        int sz = lin ^ ((px & 7) << 4);
                        av[mt] = *reinterpret_cast<const f16x8*>(sb + sz);
                    }
#pragma unroll
                    for (int mt = 0; mt < 4; ++mt)
                        acc[mt] = __builtin_amdgcn_mfma_f32_16x16x32_f16(av[mt], bv, acc[mt], 0, 0, 0);
                }
            }
        }
    }
    const float bb = bias[cow];
#pragma unroll
    for (int mt = 0; mt < 4; ++mt) {
#pragma unroll
        for (int r = 0; r < 4; ++r) {
            int Q = mt * 16 + g * 4 + r;
            size_t pix = ((size_t)b * 64 + P) * 64 + Q;
            float z = acc[mt][r] + bb;
            z = z > 0.f ? z : expm1f(z);
            float res = z * sm[pix * 128 + cow];
            if (W16) {
                out16[(((size_t)b * 66 + P + 1) * 66 + Q + 1) * 128 + cow] = (_Float16)res;
            } else {
                out[pix * 128 + cow] = res;
            }
        }
    }
}

extern "C" void kernel_launch(void* const* d_in, const int* in_sizes, int n_in,
                              void* d_out, int out_size, void* d_ws, size_t ws_size,
                              hipStream_t stream) {
    const float* x    = (const float*)d_in[0];
    const float* mask = (const float*)d_in[1];
    const float* w1   = (const float*)d_in[2];
    const float* b1   = (const float*)d_in[3];
    const float* dw1  = (const float*)d_in[4];
    const float* pw1  = (const float*)d_in[5];
    const float* db1  = (const float*)d_in[6];
    const float* w2   = (const float*)d_in[7];
    const float* b2   = (const float*)d_in[8];
    const float* dw2  = (const float*)d_in[9];
    const float* pw2  = (const float*)d_in[10];
    const float* db2  = (const float*)d_in[11];

    float* out_a = (float*)d_out;            // (8,64,64,128)
    float* out_c = out_a + 4194304;          // (8,32,32,1024)

    char* wsb = (char*)d_ws;
    float* Tbuf    = (float*)(wsb + BOFF_T);
    float* sp      = (float*)(wsb + BOFF_SP);
    float* invd    = (float*)(wsb + BOFF_INVD);
    _Float16* sp16 = (_Float16*)(wsb + BOFF_SP16);
    _Float16* bf16b = (_Float16*)(wsb + BOFF_BF16);
    _Float16* yp16 = (_Float16*)(wsb + BOFF_YP16);
    _Float16* bp16 = (_Float16*)(wsb + BOFF_BP16);
    float* yup     = (float*)(wsb + BOFF_YUP);
    float* smb     = (float*)(wsb + BOFF_SM);
    _Float16* p316 = (_Float16*)(wsb + BOFF_P316);
    _Float16* p316b = (_Float16*)(wsb + BOFF_P316B);
    _Float16* x16  = (_Float16*)(wsb + BOFF_X16);
    _Float16* wt1  = (_Float16*)(wsb + BOFF_WT1);
    _Float16* wt2  = (_Float16*)(wsb + BOFF_WT2);
    _Float16* pw1t = (_Float16*)(wsb + BOFF_PW1);
    _Float16* pw2t = (_Float16*)(wsb + BOFF_PW2);
    float* m0      = (float*)(wsb + BOFF_M0);
    float* mmb     = (float*)(wsb + BOFF_MM);

    // phase A: mask + correlation (fp16 MFMA) -> Tbuf; fused fuse+softmax -> out_c/yp16
    k_mask_pool<<<8192, 256, 0, stream>>>(mask, m0);
    k_mask_dilate<<<32, 256, 0, stream>>>(m0, mmb);
    k_srcpad<<<4624, 256, 0, stream>>>(x, sp, sp16);
    k_invd<<<512, 256, 0, stream>>>(sp, invd);
    k_wt16<<<576, 256, 0, stream>>>(w1, wt1, 128);
    k_wt16<<<1152, 256, 0, stream>>>(w2, wt2, 256);
    k_pw16<<<64, 256, 0, stream>>>(pw1, pw1t, 128);
    k_pw16<<<128, 256, 0, stream>>>(pw2, pw2t, 256);
    k_corr_B16<<<4608, 256, 0, stream>>>(sp, invd, bf16b);
    k_corr_mfma<<<2048, 256, 0, stream>>>(sp16, bf16b, Tbuf);
    k_fsm<<<8192, 256, 0, stream>>>(Tbuf, mmb, out_c, yp16);   // Tbuf dead after
    // phase B: deconv (fp16 MFMA, XCD=batch) -> yup (bp16 overlays dead Tbuf)
    k_deconv_B16<<<4608, 256, 0, stream>>>(x, bp16);
    hipMemsetAsync(yup, 0, (size_t)4194304 * sizeof(float), stream);
    k_deconv_mfma<<<2304, 256, 0, stream>>>(yp16, bp16, yup);
    // phase C: gated conv 1 (all fp16 single-plane)
    k_pad16<<<2178, 256, 0, stream>>>(yup, p316);   // yup dead after this
    k_pad16<<<2178, 256, 0, stream>>>(x, x16);      // overlaps dead yup tail (stream-ordered)
    hipMemsetAsync(p316b, 0, (size_t)8 * 66 * 66 * 128 * sizeof(_Float16), stream); // zero halo
    k_dwpw_mfma<128><<<1024, 256, 0, stream>>>(p316, nullptr, dw1, pw1t, db1, smb);
    k_conv_lds<128, 1><<<1024, 256, 0, stream>>>(p316, nullptr, wt1, b1, smb,
                                                 nullptr, p316b);   // a1 -> fp16 padded directly
    // phase D: gated conv 2 (concat(a1, x))
    k_dwpw_mfma<256><<<1024, 256, 0, stream>>>(p316b, x16, dw2, pw2t, db2, smb);
    k_conv_lds<256, 0><<<1024, 256, 0, stream>>>(p316b, x16, wt2, b2, smb, out_a, nullptr);
}

// Round 27
// 370.129 us; speedup vs baseline: 1.1371x; 1.1371x over previous
//
#include <hip/hip_runtime.h>
#include <hip/hip_bf16.h>

// B=8, H=W=64, C=128, rate=2 -> k=3, h=w=32, L=1024
// ROUND-25 BEST CONFIGURATION (371 us, absmax 2.44e-4) — restored after the
// M-tile-32 experiment regressed (r26: 421 us, MfmaUtil 8.9%).
// Workspace (72,433,664 bytes), time-multiplexed (liveness checked):
//  phase A: Tbuf(corr out) [0,33.55M); sp [33.55,38.29M) invd [38.29,38.81M)
//           sp16 [38.81,41.18M) bf16 [41.18,60.06M)
//  fsm:     reads Tbuf -> out_c + yp16 [33.55,50.33M)
//  deconv:  bp16 [0,18.87M) (after fsm), yup [50.33,67.11M)
//  phase C/D: SM [0,16.78M) P316 [16.78,25.70M) P316B [25.70,34.62M)
//             X16 [42.48,51.40M)  (overlaps stream-ordered)
//  static:  wt1 [69.24M) wt2 [69.83M) pw1 [71.01M) pw2 [71.04M) m0/mm [71.11M)

#define BOFF_T       0
#define BOFF_SP      33554432
#define BOFF_INVD    38289408
#define BOFF_SP16    38813696
#define BOFF_BF16    41181184
#define BOFF_YP16    33554432
#define BOFF_BP16    0
#define BOFF_YUP     50331648
#define BOFF_SM      0
#define BOFF_P316    16777216
#define BOFF_P316B   25698304
#define BOFF_X16     42475520
#define BOFF_WT1     69238784
#define BOFF_WT2     69828608
#define BOFF_PW1     71008256
#define BOFF_PW2     71041024
#define BOFF_M0      71106560
#define BOFF_MM      71139328

typedef float f32x4 __attribute__((ext_vector_type(4)));
typedef _Float16 f16x8 __attribute__((ext_vector_type(8)));

__global__ __launch_bounds__(256) void k_mask_pool(const float* __restrict__ mask, float* __restrict__ m0) {
    int blk = blockIdx.x;
    int b = blk >> 10, pq = blk & 1023, p = pq >> 5, q = pq & 31;
    int t = threadIdx.x, dy = t >> 4, dx = t & 15;
    float v = mask[((size_t)(b * 512 + p * 16 + dy)) * 512 + q * 16 + dx];
#pragma unroll
    for (int o = 32; o; o >>= 1) v = fmaxf(v, __shfl_xor(v, o));
    __shared__ float s[4];
    if ((t & 63) == 0) s[t >> 6] = v;
    __syncthreads();
    if (t == 0) m0[blk] = fmaxf(fmaxf(s[0], s[1]), fmaxf(s[2], s[3]));
}

__global__ void k_mask_dilate(const float* __restrict__ m0, float* __restrict__ mm) {
    int idx = blockIdx.x * 256 + threadIdx.x;
    if (idx >= 8192) return;
    int b = idx >> 10, pq = idx & 1023, p = pq >> 5, q = pq & 31;
    float v = -1e30f;
    for (int di = -1; di <= 1; ++di)
        for (int dj = -1; dj <= 1; ++dj) {
            int pp = p + di, qq = q + dj;
            if (pp >= 0 && pp < 32 && qq >= 0 && qq < 32)
                v = fmaxf(v, m0[(b << 10) + pp * 32 + qq]);
        }
    mm[idx] = 1.0f - v;
}

// srcpad + fp16 conversion fused (single pass)
__global__ void k_srcpad(const float* __restrict__ x, float* __restrict__ sp,
                         _Float16* __restrict__ sp16) {
    int idx = blockIdx.x * 256 + threadIdx.x;
    if (idx >= 8 * 34 * 34 * 128) return;
    int c = idx & 127;
    int r = idx >> 7;
    int xx = r % 34; r /= 34;
    int yy = r % 34; int b = r / 34;
    float v = 0.f;
    if (yy >= 1 && yy <= 32 && xx >= 1 && xx <= 32)
        v = x[(((size_t)(b * 64 + (yy - 1) * 2)) * 64 + (xx - 1) * 2) * 128 + c];
    sp[idx] = v;
    sp16[idx] = (_Float16)v;
}

__global__ void k_invd(const float* __restrict__ sp, float* __restrict__ invd) {
    int idx = blockIdx.x * 256 + threadIdx.x;
    if (idx >= 1024 * 128) return;
    int c = idx & 127, l = idx >> 7, lh = l >> 5, lw = l & 31;
    float s = 0.f;
    for (int b = 0; b < 8; ++b)
#pragma unroll
        for (int i = 0; i < 3; ++i)
#pragma unroll
            for (int j = 0; j < 3; ++j) {
                float v = sp[(((size_t)(b * 34 + lh + i)) * 34 + (lw + j)) * 128 + c];
                s += v * v;
            }
    invd[idx] = 1.0f / fmaxf(s, 1e-8f);
}

// Bf16[b][l][ij][c] = sp[b][lh+i][lw+j][c] * invd[l][c], fp16.
__global__ void k_corr_B16(const float* __restrict__ sp, const float* __restrict__ invd,
                           _Float16* __restrict__ bf) {
    int idx = blockIdx.x * 256 + threadIdx.x;
    if (idx >= 1179648) return;
    int c8 = idx & 15; int rest = idx >> 4;
    int ij = rest % 9; int rest2 = rest / 9;
    int l = rest2 & 1023, b = rest2 >> 10;
    int lh = l >> 5, lw = l & 31;
    int i = (ij >= 6) ? 2 : (ij >= 3 ? 1 : 0);
    int j = ij - 3 * i;
    int c0 = c8 * 8;
    const float* s = sp + (((size_t)(b * 34 + lh + i)) * 34 + (lw + j)) * 128 + c0;
    const float* dv = invd + l * 128 + c0;
    f16x8 h;
#pragma unroll
    for (int u = 0; u < 8; ++u) h[u] = (_Float16)(s[u] * dv[u]);
    size_t off = ((size_t)(b * 1024 + l)) * 1152 + ij * 128 + c0;
    *reinterpret_cast<f16x8*>(bf + off) = h;
}

// Bp16[b][ij][c][l] = x[b][2lh+ip][2lw+jp][c] (0 OOB), fp16.
__global__ void k_deconv_B16(const float* __restrict__ x, _Float16* __restrict__ bp) {
    int idx = blockIdx.x * 256 + threadIdx.x;
    if (idx >= 1179648) return;
    int l8 = idx & 127; int rest = idx >> 7;
    int c = rest & 127; int rest2 = rest >> 7;
    int ij = rest2 % 9; int b = rest2 / 9;
    int ip = (ij >= 6) ? 2 : (ij >= 3 ? 1 : 0);
    int jp = ij - 3 * ip;
    int l0 = l8 * 8;
    int lh = l0 >> 5, lw0 = l0 & 31;
    int rr = 2 * lh + ip;
    f16x8 h;
#pragma unroll
    for (int u = 0; u < 8; ++u) {
        int ss = 2 * (lw0 + u) + jp;
        float v = (rr < 64 && ss < 64) ? x[(((size_t)(b * 64 + rr)) * 64 + ss) * 128 + c] : 0.f;
        h[u] = (_Float16)v;
    }
    size_t off = (((size_t)(b * 9 + ij)) * 128 + c) * 1024 + l0;
    *reinterpret_cast<f16x8*>(bp + off) = h;
}

// corr MFMA fp16: M-tile 64, N-tile 128, K-step 64, 256 thr / 4 waves (nn=2),
// depth-2 prefetch, XCD-swizzled grid (1024) -> 4 blocks/CU.
__global__ __launch_bounds__(256) void k_corr_mfma(const _Float16* __restrict__ sp16,
                                                   const _Float16* __restrict__ bf,
                                                   float* __restrict__ outy) {
    const int bid = blockIdx.x;
    const int xcd = bid & 7, slot = bid >> 3;   // slot in [0,128)
    const int tm = slot & 15, pg = slot >> 4;   // pg in [0,8)
    const int panel = pg * 8 + xcd;             // [0,64)
    const int b = panel >> 3, tn = panel & 7;
    __shared__ _Float16 Aa[64][40];
    __shared__ _Float16 Ab[64][40];
    const int tid = threadIdx.x;
    const int w = tid >> 6, lane = tid & 63, m = lane & 15, g = lane >> 4;
    f32x4 acc[4][2];
#pragma unroll
    for (int mf = 0; mf < 4; ++mf)
#pragma unroll
        for (int nn = 0; nn < 2; ++nn) acc[mf][nn] = f32x4{0.f, 0.f, 0.f, 0.f};
    const int srow = tid >> 2, scc = (tid & 3) * 8;
    const int pq = tm * 64 + srow, p = pq >> 5, q = pq & 31;
    const int col0 = tn * 128 + w * 32 + m;
    const size_t boff0 = ((size_t)b * 1024 + col0) * 1152 + g * 8;
    const size_t boff1 = ((size_t)b * 1024 + col0 + 16) * 1152 + g * 8;

    auto aoff = [&](int kt) -> size_t {
        int ij = kt >> 7;
        int i = (ij >= 6) ? 2 : (ij >= 3 ? 1 : 0);
        int j = ij - 3 * i;
        int c0 = (kt & 127) + scc;
        return (((size_t)(b * 34 + p + i)) * 34 + (q + j)) * 128 + c0;
    };
    f16x8 aq_a = *reinterpret_cast<const f16x8*>(sp16 + aoff(0));
    f16x8 aq_b = *reinterpret_cast<const f16x8*>(sp16 + aoff(32));
    f16x8 aq2_a = *reinterpret_cast<const f16x8*>(sp16 + aoff(64));
    f16x8 aq2_b = *reinterpret_cast<const f16x8*>(sp16 + aoff(96));
    f16x8 b0q_a = *reinterpret_cast<const f16x8*>(bf + boff0);
    f16x8 b0q_b = *reinterpret_cast<const f16x8*>(bf + boff0 + 32);
    f16x8 b1q_a = *reinterpret_cast<const f16x8*>(bf + boff1);
    f16x8 b1q_b = *reinterpret_cast<const f16x8*>(bf + boff1 + 32);
    f16x8 b0q2_a = *reinterpret_cast<const f16x8*>(bf + boff0 + 64);
    f16x8 b0q2_b = *reinterpret_cast<const f16x8*>(bf + boff0 + 96);
    f16x8 b1q2_a = *reinterpret_cast<const f16x8*>(bf + boff1 + 64);
    f16x8 b1q2_b = *reinterpret_cast<const f16x8*>(bf + boff1 + 96);

    for (int kt = 0; kt < 1152; kt += 64) {
        __syncthreads();
        *reinterpret_cast<f16x8*>(&Aa[srow][scc]) = aq_a;
        *reinterpret_cast<f16x8*>(&Ab[srow][scc]) = aq_b;
        __syncthreads();
        const int kt2 = (kt + 128 < 1152) ? kt + 128 : kt;
        f16x8 cb0a = b0q_a, cb0b = b0q_b, cb1a = b1q_a, cb1b = b1q_b;
        aq_a = aq2_a; aq_b = aq2_b;
        aq2_a = *reinterpret_cast<const f16x8*>(sp16 + aoff(kt2));
        aq2_b = *reinterpret_cast<const f16x8*>(sp16 + aoff(kt2 + 32));
        b0q_a = b0q2_a; b0q_b = b0q2_b;
        b1q_a = b1q2_a; b1q_b = b1q2_b;
        b0q2_a = *reinterpret_cast<const f16x8*>(bf + boff0 + kt2);
        b0q2_b = *reinterpret_cast<const f16x8*>(bf + boff0 + kt2 + 32);
        b1q2_a = *reinterpret_cast<const f16x8*>(bf + boff1 + kt2);
        b1q2_b = *reinterpret_cast<const f16x8*>(bf + boff1 + kt2 + 32);

        f16x8 av;
#pragma unroll
        for (int mf = 0; mf < 4; ++mf) {
            av = *reinterpret_cast<const f16x8*>(&Aa[mf * 16 + m][g * 8]);
            acc[mf][0] = __builtin_amdgcn_mfma_f32_16x16x32_f16(av, cb0a, acc[mf][0], 0, 0, 0);
            acc[mf][1] = __builtin_amdgcn_mfma_f32_16x16x32_f16(av, cb1a, acc[mf][1], 0, 0, 0);
            av = *reinterpret_cast<const f16x8*>(&Ab[mf * 16 + m][g * 8]);
            acc[mf][0] = __builtin_amdgcn_mfma_f32_16x16x32_f16(av, cb0b, acc[mf][0], 0, 0, 0);
            acc[mf][1] = __builtin_amdgcn_mfma_f32_16x16x32_f16(av, cb1b, acc[mf][1], 0, 0, 0);
        }
    }
#pragma unroll
    for (int mf = 0; mf < 4; ++mf) {
        int row = tm * 64 + mf * 16 + g * 4;
#pragma unroll
        for (int nn = 0; nn < 2; ++nn) {
            int col = col0 + nn * 16;
#pragma unroll
            for (int r = 0; r < 4; ++r)
                outy[((size_t)b << 20) + (size_t)(row + r) * 1024 + col] = acc[mf][nn][r];
        }
    }
}

// deconv MFMA fp16: M-tile 64, K-step 64, 256 thr / 4 waves (nn=2), depth-2
// prefetch, XCD=batch mapping (working set L2-resident). Grid 1152.
__global__ __launch_bounds__(256) void k_deconv_mfma(const _Float16* __restrict__ yp16,
                                                     const _Float16* __restrict__ bp,
                                                     float* __restrict__ yup) {
    const int bid = blockIdx.x;
    const int b = bid & 7;                      // xcd == batch
    const int slot = bid >> 3;                  // [0,144)
    const int tn = slot % 9;
    const int tm = slot / 9;                    // [0,16)
    __shared__ _Float16 Aa[64][40];
    __shared__ _Float16 Ab[64][40];
    const int tid = threadIdx.x;
    const int w = tid >> 6, lane = tid & 63, m = lane & 15, g = lane >> 4;
    f32x4 acc[4][2];
#pragma unroll
    for (int mf = 0; mf < 4; ++mf)
#pragma unroll
        for (int nn = 0; nn < 2; ++nn) acc[mf][nn] = f32x4{0.f, 0.f, 0.f, 0.f};
    const int srow = tid >> 2, scc = (tid & 3) * 8;
    const int c0 = w * 32 + m;
    const _Float16* abase = yp16 + ((size_t)b << 20) + (size_t)(tm * 64 + srow) * 1024 + scc;
    const size_t boff0 = (((size_t)(b * 9 + tn)) * 128 + c0) * 1024 + g * 8;
    const size_t boff1 = (((size_t)(b * 9 + tn)) * 128 + c0 + 16) * 1024 + g * 8;

    f16x8 aq_a = *reinterpret_cast<const f16x8*>(abase);
    f16x8 aq_b = *reinterpret_cast<const f16x8*>(abase + 32);
    f16x8 aq2_a = *reinterpret_cast<const f16x8*>(abase + 64);
    f16x8 aq2_b = *reinterpret_cast<const f16x8*>(abase + 96);
    f16x8 b0q_a = *reinterpret_cast<const f16x8*>(bp + boff0);
    f16x8 b0q_b = *reinterpret_cast<const f16x8*>(bp + boff0 + 32);
    f16x8 b1q_a = *reinterpret_cast<const f16x8*>(bp + boff1);
    f16x8 b1q_b = *reinterpret_cast<const f16x8*>(bp + boff1 + 32);
    f16x8 b0q2_a = *reinterpret_cast<const f16x8*>(bp + boff0 + 64);
    f16x8 b0q2_b = *reinterpret_cast<const f16x8*>(bp + boff0 + 96);
    f16x8 b1q2_a = *reinterpret_cast<const f16x8*>(bp + boff1 + 64);
    f16x8 b1q2_b = *reinterpret_cast<const f16x8*>(bp + boff1 + 96);

    for (int kt = 0; kt < 1024; kt += 64) {
        __syncthreads();
        *reinterpret_cast<f16x8*>(&Aa[srow][scc]) = aq_a;
        *reinterpret_cast<f16x8*>(&Ab[srow][scc]) = aq_b;
        __syncthreads();
        const int kt2 = (kt + 128 < 1024) ? kt + 128 : kt;
        f16x8 cb0a = b0q_a, cb0b = b0q_b, cb1a = b1q_a, cb1b = b1q_b;
        aq_a = aq2_a; aq_b = aq2_b;
        aq2_a = *reinterpret_cast<const f16x8*>(abase + kt2);
        aq2_b = *reinterpret_cast<const f16x8*>(abase + kt2 + 32);
        b0q_a = b0q2_a; b0q_b = b0q2_b;
        b1q_a = b1q2_a; b1q_b = b1q2_b;
        b0q2_a = *reinterpret_cast<const f16x8*>(bp + boff0 + kt2);
        b0q2_b = *reinterpret_cast<const f16x8*>(bp + boff0 + kt2 + 32);
        b1q2_a = *reinterpret_cast<const f16x8*>(bp + boff1 + kt2);
        b1q2_b = *reinterpret_cast<const f16x8*>(bp + boff1 + kt2 + 32);

        f16x8 av;
#pragma unroll
        for (int mf = 0; mf < 4; ++mf) {
            av = *reinterpret_cast<const f16x8*>(&Aa[mf * 16 + m][g * 8]);
            acc[mf][0] = __builtin_amdgcn_mfma_f32_16x16x32_f16(av, cb0a, acc[mf][0], 0, 0, 0);
            acc[mf][1] = __builtin_amdgcn_mfma_f32_16x16x32_f16(av, cb1a, acc[mf][1], 0, 0, 0);
            av = *reinterpret_cast<const f16x8*>(&Ab[mf * 16 + m][g * 8]);
            acc[mf][0] = __builtin_amdgcn_mfma_f32_16x16x32_f16(av, cb0b, acc[mf][0], 0, 0, 0);
            acc[mf][1] = __builtin_amdgcn_mfma_f32_16x16x32_f16(av, cb1b, acc[mf][1], 0, 0, 0);
        }
    }
    const int ip = (tn >= 6) ? 2 : (tn >= 3 ? 1 : 0);
    const int jp = tn - 3 * ip;
#pragma unroll
    for (int mf = 0; mf < 4; ++mf) {
        int uvb = tm * 64 + mf * 16 + g * 4;
#pragma unroll
        for (int nn = 0; nn < 2; ++nn) {
            int c = c0 + nn * 16;
#pragma unroll
            for (int r = 0; r < 4; ++r) {
                int uv = uvb + r;
                int uu = uv >> 5, vv = uv & 31;
                int P = 2 * uu + ip, Q = 2 * vv + jp;
                if (P < 64 && Q < 64)
                    atomicAdd(&yup[(((size_t)(b * 64 + P)) * 64 + Q) * 128 + c], acc[mf][nn][r]);
            }
        }
    }
}

// FUSED fuse1+fuse2+softmax.
__global__ __launch_bounds__(256) void k_fsm(const float* __restrict__ y,
                                             const float* __restrict__ mm,
                                             float* __restrict__ outc,
                                             _Float16* __restrict__ yp16) {
    int row = blockIdx.x;               // b*1024 + s
    int b = row >> 10, s = row & 1023;
    const float* base = y + ((size_t)b << 20);
    float mmv = mm[row];
    int t0 = threadIdx.x;
    const int m0 = ((s & 31) << 5) + (s >> 5);
    float vals[4];
    float mx = -1e30f;
#pragma unroll
    for (int i = 0; i < 4; ++i) {
        int t = t0 + i * 256;
        int n0 = ((t & 31) << 5) + (t >> 5);
        float v = 0.f;
#pragma unroll
        for (int d = -1; d <= 1; ++d) {
            int mm_ = m0 + d, nn_ = n0 + d;
            if (mm_ >= 0 && mm_ < 1024 && nn_ >= 0 && nn_ < 1024) {
                int a = ((mm_ & 31) << 5) + (mm_ >> 5);
                int c = ((nn_ & 31) << 5) + (nn_ >> 5);
                float zv = base[(size_t)a * 1024 + c];
                if (a > 0 && c > 0) zv += base[(size_t)(a - 1) * 1024 + (c - 1)];
                if (a < 1023 && c < 1023) zv += base[(size_t)(a + 1) * 1024 + (c + 1)];
                v += zv;
            }
        }
        vals[i] = v * mmv * 10.0f;
        mx = fmaxf(mx, vals[i]);
    }
#pragma unroll
    for (int o = 32; o; o >>= 1) mx = fmaxf(mx, __shfl_xor(mx, o));
    __shared__ float red[8];
    if ((t0 & 63) == 0) red[t0 >> 6] = mx;
    __syncthreads();
    mx = fmaxf(fmaxf(red[0], red[1]), fmaxf(red[2], red[3]));
    float ssum = 0.f;
#pragma unroll
    for (int i = 0; i < 4; ++i) {
        vals[i] = expf(vals[i] - mx);
        ssum += vals[i];
    }
#pragma unroll
    for (int o = 32; o; o >>= 1) ssum += __shfl_xor(ssum, o);
    if ((t0 & 63) == 0) red[4 + (t0 >> 6)] = ssum;
    __syncthreads();
    ssum = red[4] + red[5] + red[6] + red[7];
    float inv = mmv / ssum;
#pragma unroll
    for (int i = 0; i < 4; ++i) {
        float pv = vals[i] * inv;
        outc[(size_t)row * 1024 + t0 + i * 256] = pv;
        yp16[(size_t)row * 1024 + t0 + i * 256] = (_Float16)pv;
    }
}

// f32 image (8,64,64,128) -> padded fp16 (8,66,66,128), zero halo
__global__ __launch_bounds__(256) void k_pad16(const float* __restrict__ in,
                                               _Float16* __restrict__ o) {
    int idx = blockIdx.x * 256 + threadIdx.x;
    int c8 = idx & 15;
    int r = idx >> 4;
    int pc = r % 66; r /= 66;
    int pr = r % 66; int b = r / 66;
    f16x8 h;
    if (pr >= 1 && pr <= 64 && pc >= 1 && pc <= 64) {
        const float* s = in + (((size_t)(b * 64 + pr - 1)) * 64 + (pc - 1)) * 128 + c8 * 8;
        float4 v0 = *reinterpret_cast<const float4*>(s);
        float4 v1 = *reinterpret_cast<const float4*>(s + 4);
        h[0] = (_Float16)v0.x; h[1] = (_Float16)v0.y; h[2] = (_Float16)v0.z; h[3] = (_Float16)v0.w;
        h[4] = (_Float16)v1.x; h[5] = (_Float16)v1.y; h[6] = (_Float16)v1.z; h[7] = (_Float16)v1.w;
    } else {
#pragma unroll
        for (int u = 0; u < 8; ++u) h[u] = (_Float16)0.f;
    }
    *reinterpret_cast<f16x8*>(o + (size_t)idx * 8) = h;
}

// (3,3,CI,128) f32 -> [9][co=128][ci] fp16
__global__ void k_wt16(const float* __restrict__ w, _Float16* __restrict__ o, int CI) {
    int idx = blockIdx.x * 256 + threadIdx.x;
    if (idx >= 9 * CI * 128) return;
    int ci = idx % CI; int rest = idx / CI;
    int co = rest & 127; int ij = rest >> 7;
    o[idx] = (_Float16)w[((size_t)ij * CI + ci) * 128 + co];
}

// pw (1,1,CI,128) f32 -> transposed fp16 [co][ci]
__global__ void k_pw16(const float* __restrict__ pw, _Float16* __restrict__ out, int CI) {
    int idx = blockIdx.x * 256 + threadIdx.x;
    if (idx >= CI * 128) return;
    int co = idx & 127, ci = idx >> 7;
    out[(size_t)co * CI + ci] = (_Float16)pw[idx];
}

// Fused depthwise 3x3 + pointwise (fp16 MFMA) + channel softmax -> smout f32.
// HALF-ROW blocks (32 px): grid 1024 = (b,P,half), 4 blocks/CU, dwacc CI/8 regs.
template <int CI>
__global__ __launch_bounds__(256) void k_dwpw_mfma(const _Float16* __restrict__ in0,
                                                   const _Float16* __restrict__ in1,
                                                   const float* __restrict__ dwW,
                                                   const _Float16* __restrict__ pwt,
                                                   const float* __restrict__ db,
                                                   float* __restrict__ smout) {
    const int bid = blockIdx.x;
    const int swz = (bid & 7) * 128 + (bid >> 3);   // XCD-contiguous
    const int b = swz >> 7;
    const int rem = swz & 127;
    const int P = rem >> 1, half = rem & 1;
    const int Q0 = half * 32;
    const int t = threadIdx.x;
    const int w = t >> 6, lane = t & 63, m = lane & 15, g = lane >> 4;
    __shared__ _Float16 Adw[32 * CI];
    __shared__ float red[2][4][32];
    char* ab = (char*)Adw;
    const int px = t & 31;
    const int grp = t >> 5;
    const int cb = grp * (CI / 8);
    float dwacc[CI / 8];
#pragma unroll
    for (int u = 0; u < CI / 8; ++u) dwacc[u] = 0.f;
#pragma unroll
    for (int i = 0; i < 3; ++i) {
#pragma unroll
        for (int j = 0; j < 3; ++j) {
            const int ij = i * 3 + j;
#pragma unroll
            for (int c8 = 0; c8 < CI / 64; ++c8) {
                const int c = cb + c8 * 8;
                const _Float16* ph = (CI == 256 && c >= 128) ? in1 : in0;
                const int cc = (CI == 256 && c >= 128) ? (c - 128) : c;
                size_t off = (((size_t)b * 66 + P + i) * 66 + Q0 + px + j) * 128 + cc;
                f16x8 vh = *reinterpret_cast<const f16x8*>(ph + off);
#pragma unroll
                for (int u = 0; u < 8; ++u)
                    dwacc[c8 * 8 + u] = fmaf((float)vh[u], dwW[ij * CI + c + u], dwacc[c8 * 8 + u]);
            }
        }
    }
#pragma unroll
    for (int c8 = 0; c8 < CI / 64; ++c8) {
        f16x8 hv;
#pragma unroll
        for (int u = 0; u < 8; ++u) hv[u] = (_Float16)dwacc[c8 * 8 + u];
        int byte = px * (CI * 2) + (cb + c8 * 8) * 2;
        int sz = byte ^ ((px & 7) << 4);
        *reinterpret_cast<f16x8*>(ab + sz) = hv;
    }
    __syncthreads();
    f32x4 acc[2][2];
#pragma unroll
    for (int mt = 0; mt < 2; ++mt)
#pragma unroll
        for (int nn = 0; nn < 2; ++nn) acc[mt][nn] = f32x4{0.f, 0.f, 0.f, 0.f};
    const int co0 = w * 32 + m;
#pragma unroll
    for (int kc = 0; kc < CI / 32; ++kc) {
        f16x8 av[2];
#pragma unroll
        for (int mt = 0; mt < 2; ++mt) {
            int prow = mt * 16 + m;
            int byte = prow * (CI * 2) + (kc * 32 + g * 8) * 2;
            int sz = byte ^ ((prow & 7) << 4);
            av[mt] = *reinterpret_cast<const f16x8*>(ab + sz);
        }
#pragma unroll
        for (int nn = 0; nn < 2; ++nn) {
            f16x8 bv = *reinterpret_cast<const f16x8*>(pwt + (size_t)(co0 + nn * 16) * CI + kc * 32 + g * 8);
#pragma unroll
            for (int mt = 0; mt < 2; ++mt)
                acc[mt][nn] = __builtin_amdgcn_mfma_f32_16x16x32_f16(av[mt], bv, acc[mt][nn], 0, 0, 0);
        }
    }
    float db0 = db[co0], db1 = db[co0 + 16];
    float mx[2][4];
#pragma unroll
    for (int mt = 0; mt < 2; ++mt)
#pragma unroll
        for (int r = 0; r < 4; ++r) {
            acc[mt][0][r] += db0;
            acc[mt][1][r] += db1;
            float v = fmaxf(acc[mt][0][r], acc[mt][1][r]);
#pragma unroll
            for (int o = 1; o <= 8; o <<= 1) v = fmaxf(v, __shfl_xor(v, o));
            mx[mt][r] = v;
        }
    if (m == 0) {
#pragma unroll
        for (int mt = 0; mt < 2; ++mt)
#pragma unroll
            for (int r = 0; r < 4; ++r) red[0][w][mt * 16 + g * 4 + r] = mx[mt][r];
    }
    __syncthreads();
    float sume[2][4];
#pragma unroll
    for (int mt = 0; mt < 2; ++mt)
#pragma unroll
        for (int r = 0; r < 4; ++r) {
            int p = mt * 16 + g * 4 + r;
            float M = fmaxf(fmaxf(red[0][0][p], red[0][1][p]), fmaxf(red[0][2][p], red[0][3][p]));
            acc[mt][0][r] = expf(acc[mt][0][r] - M);
            acc[mt][1][r] = expf(acc[mt][1][r] - M);
            float s = acc[mt][0][r] + acc[mt][1][r];
#pragma unroll
            for (int o = 1; o <= 8; o <<= 1) s += __shfl_xor(s, o);
            sume[mt][r] = s;
        }
    if (m == 0) {
#pragma unroll
        for (int mt = 0; mt < 2; ++mt)
#pragma unroll
            for (int r = 0; r < 4; ++r) red[1][w][mt * 16 + g * 4 + r] = sume[mt][r];
    }
    __syncthreads();
#pragma unroll
    for (int mt = 0; mt < 2; ++mt)
#pragma unroll
        for (int r = 0; r < 4; ++r) {
            int p = mt * 16 + g * 4 + r;
            float S = red[1][0][p] + red[1][1][p] + red[1][2][p] + red[1][3][p];
            float inv = 1.0f / S;
            size_t pix = ((size_t)b * 64 + P) * 64 + Q0 + p;
            smout[pix * 128 + co0] = acc[mt][0][r] * inv;
            smout[pix * 128 + co0 + 16] = acc[mt][1][r] * inv;
        }
}

// fp16 implicit-GEMM 3x3 conv + bias + elu + gate, LDS-staged rows.
// W16=1: write fp16 directly into padded (8,66,66,128) buffer (interior).
template <int CI, int W16>
__global__ __launch_bounds__(256, 4) void k_conv_lds(const _Float16* __restrict__ in0,
                                                     const _Float16* __restrict__ in1,
                                                     const _Float16* __restrict__ wt,
                                                     const float* __restrict__ bias,
                                                     const float* __restrict__ sm,
                                                     float* __restrict__ out,
                                                     _Float16* __restrict__ out16) {
    const int bid = blockIdx.x;
    const int idx = (bid & 7) * 128 + (bid >> 3);
    const int row = idx >> 1, cohalf = idx & 1;
    const int b = row >> 6, P = row & 63;
    const int tid = threadIdx.x;
    const int w = tid >> 6, lane = tid & 63;
    const int m = lane & 15, g = lane >> 4;
    __shared__ _Float16 S[66 * 128];
    char* sb = (char*)S;
    f32x4 acc[4];
#pragma unroll
    for (int mt = 0; mt < 4; ++mt) acc[mt] = f32x4{0.f, 0.f, 0.f, 0.f};
    const int cow = cohalf * 64 + w * 16 + m;

#pragma unroll
    for (int half = 0; half < CI / 128; ++half) {
        const _Float16* ih = (half == 0) ? in0 : in1;
        const size_t rbase0 = ((size_t)b * 66 + P) * 66 * 128;
#pragma unroll
        for (int i = 0; i < 3; ++i) {
            __syncthreads();
            const size_t rsrc = rbase0 + (size_t)i * 66 * 128;
#pragma unroll
            for (int e0 = 0; e0 < 1056; e0 += 256) {
                int e = e0 + tid;
                if (e < 1056) {
                    int px = e >> 4, c8 = e & 15;
                    int lin = px * 256 + c8 * 16;
                    int sz = lin ^ ((px & 7) << 4);
                    size_t so = rsrc + (size_t)px * 128 + c8 * 8;
                    *reinterpret_cast<f16x8*>(sb + sz) = *reinterpret_cast<const f16x8*>(ih + so);
                }
            }
            __syncthreads();
#pragma unroll
            for (int j = 0; j < 3; ++j) {
                const int ij = i * 3 + j;
                const _Float16* wp = wt + ((size_t)ij * 128 + cow) * CI + half * 128 + g * 8;
#pragma unroll
                for (int ci0 = 0; ci0 < 128; ci0 += 32) {
                    f16x8 bv = *reinterpret_cast<const f16x8*>(wp + ci0);
                    f16x8 av[4];
#pragma unroll
                    for (int mt = 0; mt < 4; ++mt) {
                        int px = mt * 16 + m + j;
                        int lin = px * 256 + ci0 * 2 + g * 16;
                        int sz = lin ^ ((px & 7) << 4);
                        av[mt] = *reinterpret_cast<const f16x8*>(sb + sz);
                    }
#pragma unroll
                    for (int mt = 0; mt < 4; ++mt)
                        acc[mt] = __builtin_amdgcn_mfma_f32_16x16x32_f16(av[mt], bv, acc[mt], 0, 0, 0);
                }
            }
        }
    }
    const float bb = bias[cow];
#pragma unroll
    for (int mt = 0; mt < 4; ++mt) {
#pragma unroll
        for (int r = 0; r < 4; ++r) {
            int Q = mt * 16 + g * 4 + r;
            size_t pix = ((size_t)b * 64 + P) * 64 + Q;
            float z = acc[mt][r] + bb;
            z = z > 0.f ? z : expm1f(z);
            float res = z * sm[pix * 128 + cow];
            if (W16) {
                out16[(((size_t)b * 66 + P + 1) * 66 + Q + 1) * 128 + cow] = (_Float16)res;
            } else {
                out[pix * 128 + cow] = res;
            }
        }
    }
}

extern "C" void kernel_launch(void* const* d_in, const int* in_sizes, int n_in,
                              void* d_out, int out_size, void* d_ws, size_t ws_size,
                              hipStream_t stream) {
    const float* x    = (const float*)d_in[0];
    const float* mask = (const float*)d_in[1];
    const float* w1   = (const float*)d_in[2];
    const float* b1   = (const float*)d_in[3];
    const float* dw1  = (const float*)d_in[4];
    const float* pw1  = (const float*)d_in[5];
    const float* db1  = (const float*)d_in[6];
    const float* w2   = (const float*)d_in[7];
    const float* b2   = (const float*)d_in[8];
    const float* dw2  = (const float*)d_in[9];
    const float* pw2  = (const float*)d_in[10];
    const float* db2  = (const float*)d_in[11];

    float* out_a = (float*)d_out;            // (8,64,64,128)
    float* out_c = out_a + 4194304;          // (8,32,32,1024)

    char* wsb = (char*)d_ws;
    float* Tbuf    = (float*)(wsb + BOFF_T);
    float* sp      = (float*)(wsb + BOFF_SP);
    float* invd    = (float*)(wsb + BOFF_INVD);
    _Float16* sp16 = (_Float16*)(wsb + BOFF_SP16);
    _Float16* bf16b = (_Float16*)(wsb + BOFF_BF16);
    _Float16* yp16 = (_Float16*)(wsb + BOFF_YP16);
    _Float16* bp16 = (_Float16*)(wsb + BOFF_BP16);
    float* yup     = (float*)(wsb + BOFF_YUP);
    float* smb     = (float*)(wsb + BOFF_SM);
    _Float16* p316 = (_Float16*)(wsb + BOFF_P316);
    _Float16* p316b = (_Float16*)(wsb + BOFF_P316B);
    _Float16* x16  = (_Float16*)(wsb + BOFF_X16);
    _Float16* wt1  = (_Float16*)(wsb + BOFF_WT1);
    _Float16* wt2  = (_Float16*)(wsb + BOFF_WT2);
    _Float16* pw1t = (_Float16*)(wsb + BOFF_PW1);
    _Float16* pw2t = (_Float16*)(wsb + BOFF_PW2);
    float* m0      = (float*)(wsb + BOFF_M0);
    float* mmb     = (float*)(wsb + BOFF_MM);

    // phase A: mask + correlation (fp16 MFMA) -> Tbuf; fused fuse+softmax -> out_c/yp16
    k_mask_pool<<<8192, 256, 0, stream>>>(mask, m0);
    k_mask_dilate<<<32, 256, 0, stream>>>(m0, mmb);
    k_srcpad<<<4624, 256, 0, stream>>>(x, sp, sp16);
    k_invd<<<512, 256, 0, stream>>>(sp, invd);
    k_wt16<<<576, 256, 0, stream>>>(w1, wt1, 128);
    k_wt16<<<1152, 256, 0, stream>>>(w2, wt2, 256);
    k_pw16<<<64, 256, 0, stream>>>(pw1, pw1t, 128);
    k_pw16<<<128, 256, 0, stream>>>(pw2, pw2t, 256);
    k_corr_B16<<<4608, 256, 0, stream>>>(sp, invd, bf16b);
    k_corr_mfma<<<1024, 256, 0, stream>>>(sp16, bf16b, Tbuf);
    k_fsm<<<8192, 256, 0, stream>>>(Tbuf, mmb, out_c, yp16);   // Tbuf dead after
    // phase B: deconv (fp16 MFMA, XCD=batch) -> yup (bp16 overlays dead Tbuf)
    k_deconv_B16<<<4608, 256, 0, stream>>>(x, bp16);
    hipMemsetAsync(yup, 0, (size_t)4194304 * sizeof(float), stream);
    k_deconv_mfma<<<1152, 256, 0, stream>>>(yp16, bp16, yup);
    // phase C: gated conv 1 (all fp16 single-plane)
    k_pad16<<<2178, 256, 0, stream>>>(yup, p316);   // yup dead after this
    k_pad16<<<2178, 256, 0, stream>>>(x, x16);      // overlaps dead yup tail (stream-ordered)
    hipMemsetAsync(p316b, 0, (size_t)8 * 66 * 66 * 128 * sizeof(_Float16), stream); // zero halo
    k_dwpw_mfma<128><<<1024, 256, 0, stream>>>(p316, nullptr, dw1, pw1t, db1, smb);
    k_conv_lds<128, 1><<<1024, 256, 0, stream>>>(p316, nullptr, wt1, b1, smb,
                                                 nullptr, p316b);   // a1 -> fp16 padded directly
    // phase D: gated conv 2 (concat(a1, x))
    k_dwpw_mfma<256><<<1024, 256, 0, stream>>>(p316b, x16, dw2, pw2t, db2, smb);
    k_conv_lds<256, 0><<<1024, 256, 0, stream>>>(p316b, x16, wt2, b2, smb, out_a, nullptr);
}